// Round 2
// baseline (161.418 us; speedup 1.0000x reference)
//
#include <hip/hip_runtime.h>

// SE(3) exp + point transform — persistent-block, double-buffered register
// pipeline. Round 0 (LDS-staged) and round 1 (pure-register, short blocks)
// both measured identically (~54 us, 2.46 TB/s): the limiter is wave
// granularity, not coalescing or barriers. Every 3 KB of traffic paid a full
// wave launch + dofs load + ~500-cycle transcendental SE3 chain, so loads
// were in flight only a fraction of each wave's lifetime.
//
// Now: one block per (b,t). SE3 computed ONCE per block (hoisted to SGPRs),
// then 4 tiles of 1024 points are streamed through a 2-deep register
// prefetch pipeline: while tile k is transformed+stored, tile k+1 is already
// in flight and tile k+2 is issued as soon as buffer A/B frees. Waves keep
// ~2 tiles (6 KB) of reads outstanding continuously.

__device__ __forceinline__ float rfl(float x) {
    // block-uniform value -> SGPR (all lanes hold identical values)
    return __uint_as_float(__builtin_amdgcn_readfirstlane(__float_as_uint(x)));
}

__global__ __launch_bounds__(256) void se3_apply_kernel(
    const float* __restrict__ X,      // (BT, N, 3) flattened
    const float* __restrict__ dofs,   // (BT, 6)
    float* __restrict__ out,
    int n3)                            // floats per (b,t) = N*3
{
    const int bt = blockIdx.x;
    const int t  = threadIdx.x;
    const long long base = (long long)bt * (long long)n3;
    const int nIter = (n3 + 3071) / 3072;   // tiles of 3072 floats (1024 pts)
    const int f4    = t * 3;                // this thread's float4 offset in a tile
    const int slotF = t * 12;               // this thread's float offset in a tile

    const float4* __restrict__ Xp = (const float4*)(X + base);
    float4*       __restrict__ Op = (float4*)(out + base);

    // ---- prologue: issue loads for tiles 0 and 1 before the SE3 chain ----
    float4 a0, a1, a2, b0, b1, b2;
    if ((slotF + 12) <= n3) {
        a0 = Xp[f4]; a1 = Xp[f4 + 1]; a2 = Xp[f4 + 2];
    }
    if (nIter > 1 && (3072 + slotF + 12) <= n3) {
        b0 = Xp[768 + f4]; b1 = Xp[768 + f4 + 1]; b2 = Xp[768 + f4 + 2];
    }

    // ---- SE(3) exponential (block-uniform; overlaps the in-flight loads) ----
    const float* d = dofs + bt * 6;
    const float tx = d[0], ty = d[1], tz = d[2];
    const float wx = d[3], wy = d[4], wz = d[5];

    const float nrm2  = wx * wx + wy * wy + wz * wz;
    const float th2   = fmaxf(nrm2, 1e-4f);      // jnp.clip(nrms, 1e-4) (min only)
    const float theta = sqrtf(th2);
    const float st = sinf(theta);
    const float ct = cosf(theta);
    const float f1 = st / theta;
    const float f2 = (1.0f - ct) / th2;
    const float f3 = (theta - st) / (th2 * theta);

    const float xx = wx * wx, yy = wy * wy, zz = wz * wz;
    const float xy = wx * wy, xz = wx * wz, yz = wy * wz;

    const float R00 = rfl(1.0f - f2 * (yy + zz));
    const float R01 = rfl(f2 * xy - f1 * wz);
    const float R02 = rfl(f2 * xz + f1 * wy);
    const float R10 = rfl(f2 * xy + f1 * wz);
    const float R11 = rfl(1.0f - f2 * (xx + zz));
    const float R12 = rfl(f2 * yz - f1 * wx);
    const float R20 = rfl(f2 * xz - f1 * wy);
    const float R21 = rfl(f2 * yz + f1 * wx);
    const float R22 = rfl(1.0f - f2 * (xx + yy));

    const float V00 = 1.0f - f3 * (yy + zz);
    const float V01 = f3 * xy - f2 * wz;
    const float V02 = f3 * xz + f2 * wy;
    const float V10 = f3 * xy + f2 * wz;
    const float V11 = 1.0f - f3 * (xx + zz);
    const float V12 = f3 * yz - f2 * wx;
    const float V20 = f3 * xz - f2 * wy;
    const float V21 = f3 * yz + f2 * wx;
    const float V22 = 1.0f - f3 * (xx + yy);

    const float Tx = rfl(V00 * tx + V01 * ty + V02 * tz);
    const float Ty = rfl(V10 * tx + V11 * ty + V12 * tz);
    const float Tz = rfl(V20 * tx + V21 * ty + V22 * tz);

    // transform 3 float4s (4 points) and store at float4 offset 'of'
    auto xform = [&](const float4& v0, const float4& v1, const float4& v2, int of) {
        const float x0 = v0.x, y0 = v0.y, z0 = v0.z;
        const float x1 = v0.w, y1 = v1.x, z1 = v1.y;
        const float x2 = v1.z, y2 = v1.w, z2 = v2.x;
        const float x3 = v2.y, y3 = v2.z, z3 = v2.w;

        float4 o0, o1, o2;
        o0.x = fmaf(R00, x0, fmaf(R01, y0, fmaf(R02, z0, Tx)));
        o0.y = fmaf(R10, x0, fmaf(R11, y0, fmaf(R12, z0, Ty)));
        o0.z = fmaf(R20, x0, fmaf(R21, y0, fmaf(R22, z0, Tz)));
        o0.w = fmaf(R00, x1, fmaf(R01, y1, fmaf(R02, z1, Tx)));
        o1.x = fmaf(R10, x1, fmaf(R11, y1, fmaf(R12, z1, Ty)));
        o1.y = fmaf(R20, x1, fmaf(R21, y1, fmaf(R22, z1, Tz)));
        o1.z = fmaf(R00, x2, fmaf(R01, y2, fmaf(R02, z2, Tx)));
        o1.w = fmaf(R10, x2, fmaf(R11, y2, fmaf(R12, z2, Ty)));
        o2.x = fmaf(R20, x2, fmaf(R21, y2, fmaf(R22, z2, Tz)));
        o2.y = fmaf(R00, x3, fmaf(R01, y3, fmaf(R02, z3, Tx)));
        o2.z = fmaf(R10, x3, fmaf(R11, y3, fmaf(R12, z3, Ty)));
        o2.w = fmaf(R20, x3, fmaf(R21, y3, fmaf(R22, z3, Tz)));

        Op[of] = o0; Op[of + 1] = o1; Op[of + 2] = o2;
    };

    // ---- main loop: unrolled x2 over the A/B double buffer, prefetch dist 2 ----
    for (int k = 0; k < nIter; k += 2) {
        // even tile k (buffer A)
        if ((k * 3072 + slotF + 12) <= n3)
            xform(a0, a1, a2, k * 768 + f4);
        if ((k + 2) < nIter && ((k + 2) * 3072 + slotF + 12) <= n3) {
            const int p = (k + 2) * 768 + f4;
            a0 = Xp[p]; a1 = Xp[p + 1]; a2 = Xp[p + 2];
        }
        // odd tile k+1 (buffer B)
        if ((k + 1) < nIter) {
            if (((k + 1) * 3072 + slotF + 12) <= n3)
                xform(b0, b1, b2, (k + 1) * 768 + f4);
            if ((k + 3) < nIter && ((k + 3) * 3072 + slotF + 12) <= n3) {
                const int p = (k + 3) * 768 + f4;
                b0 = Xp[p]; b1 = Xp[p + 1]; b2 = Xp[p + 2];
            }
        }
    }

    // ---- scalar tail: partial slot in the last tile (whole points only).
    // Neighboring partial threads may rewrite identical values — benign.
    const int myLast = (nIter - 1) * 3072 + slotF;
    if (myLast < n3 && (myLast + 12) > n3) {
        for (int f = myLast; f + 3 <= n3; f += 3) {
            const float px = X[base + f], py = X[base + f + 1], pz = X[base + f + 2];
            out[base + f + 0] = fmaf(R00, px, fmaf(R01, py, fmaf(R02, pz, Tx)));
            out[base + f + 1] = fmaf(R10, px, fmaf(R11, py, fmaf(R12, pz, Ty)));
            out[base + f + 2] = fmaf(R20, px, fmaf(R21, py, fmaf(R22, pz, Tz)));
        }
    }
}

extern "C" void kernel_launch(void* const* d_in, const int* in_sizes, int n_in,
                              void* d_out, int out_size, void* d_ws, size_t ws_size,
                              hipStream_t stream) {
    const float* X    = (const float*)d_in[0];
    const float* dofs = (const float*)d_in[1];
    float* out        = (float*)d_out;

    const int BT = in_sizes[1] / 6;            // 64*28 = 1792
    const int n3 = in_sizes[0] / BT;           // 4096*3 = 12288 floats per bt

    dim3 grid((unsigned)BT);                   // one persistent block per (b,t)
    se3_apply_kernel<<<grid, 256, 0, stream>>>(X, dofs, out, n3);
}